// Round 18
// baseline (155.516 us; speedup 1.0000x reference)
//
#include <hip/hip_runtime.h>

// Weighted Chamfer, B=4, N=M=8192, D=3, fp32 in/out.
// out = (1/B)*[ sum_b sum_n w*min_m d2 + sum_b sum_m min_n d2 ]
//
// One v_mfma_f32_32x32x16_bf16 yields a 32x32 tile of d2 = s2 + t2 - 2 s.t
// via K-slot packing with split-bf16 compensation (verified r2-r17):
//   A(plain)  half0 {hx,hx,lx,hy,hy,ly,hz,hz} half1 {lz,h2,l2,1,1,0,0,0}
//   B(-2 scl) half0 {nhx,nlx,nhx,nhy,nly,nhy,nhz,nlz} half1 {nhz,1,1,h2,l2,0,0,0}
//   Error ~1e-5 (threshold 5.76). C/D layout: col=lane&31.
// Transposed operands (r8): DB = A staged in LDS, queries = B in registers ->
// per-lane scalar running min. i32-domain min (r13) folds to v_min3_i32.
// Self-packing (r14): no prep kernel; -2*bf16 in int bits ((h^0x8000)+0x80).
// Reg rule (r16): body needs >= ~100-reg budget; launch_bounds(256,4) only.
//
// Round 18: FUSE the reduce kernel into scan via distributed last-block
// finishers. Each (dir,b,qb) group has NCHG=8 contributing blocks and a
// ticket counter: release = __threadfence() + atomicAdd(ticket); the block
// drawing ticket NCHG-1 acquires (atomic RMW + __threadfence) and reduces
// its 512 queries (8-chunk min, weight, block-reduce, one atomicAdd to out).
// 128 finishers overlap with still-scanning blocks -> the reduce dispatch
// and its inter-kernel gap (~4-6 us) disappear. Counters + out zeroed by
// hipMemsetAsync (capture-safe memset nodes; not on the forbidden list).

typedef short bf16x8 __attribute__((ext_vector_type(8)));
typedef float f32x16 __attribute__((ext_vector_type(16)));

#define BB 4
#define NP 8192
#define RF 4                     // query-frags per wave (128 queries)
#define WAVES 4                  // 256 threads; 512 queries per block
#define QBLOCKS 16               // 8192 / 512
#define CFRAGS 32                // DB frags per LDS stage (1024 pts, 32 KB)
#define NCHG 8                   // DB chunks (8192 / 1024)

__device__ __forceinline__ int smin3(int a, int b, int c) {
    int m = a < b ? a : b;
    return (m < c) ? m : c;      // folds to v_min3_i32
}
__device__ __forceinline__ unsigned short bf16r(float x) {
    unsigned u = __float_as_uint(x);
    unsigned r = u + 0x7FFFu + ((u >> 16) & 1u);
    return (unsigned short)(r >> 16);
}
__device__ __forceinline__ float bf16f(unsigned short h) {
    return __uint_as_float(((unsigned)h) << 16);
}
// -2 * bf16(h), exact in bits (sign flip + exponent+1); h==+-0 -> tiny
// denormal ~1e-38 whose products are << 1e-5 packing error.
__device__ __forceinline__ unsigned short neg2(unsigned short h) {
    return (unsigned short)((h ^ 0x8000u) + 0x0080u);
}

struct Pack {
    unsigned short hx, lx, hy, ly, hz, lz, h2, l2;
};
__device__ __forceinline__ Pack mkpack(float x, float y, float z) {
    Pack p;
    p.hx = bf16r(x); p.lx = bf16r(x - bf16f(p.hx));
    p.hy = bf16r(y); p.ly = bf16r(y - bf16f(p.hy));
    p.hz = bf16r(z); p.lz = bf16r(z - bf16f(p.hz));
    float n2 = x * x + y * y + z * z;
    p.h2 = bf16r(n2); p.l2 = bf16r(n2 - bf16f(p.h2));
    return p;
}

#define ONE 0x3F80u

// ---- scan + fused finisher ----
__global__ __launch_bounds__(256, 4) void scan_kernel(
    const float* __restrict__ src, const float* __restrict__ tgt,
    const float* __restrict__ weights,
    float* __restrict__ part,   // part[dir][b][ch][query]
    int* __restrict__ tickets,  // tickets[dir][b][qb], pre-zeroed
    float* __restrict__ out)    // pre-zeroed
{
    __shared__ uint4 ash[CFRAGS * 64];          // 32 KB DB stage (A-packs)
    const int tid = threadIdx.x;
    const int lane = tid & 63, wave = tid >> 6;
    const int qb = blockIdx.x, b = blockIdx.y;
    const int dir = blockIdx.z >> 3, ch = blockIdx.z & (NCHG - 1);

    // dir 0: queries = source, DB = target; dir 1 mirrored.
    const float* dbc = (dir ? src : tgt) + ((size_t)b * NP + ch * 1024) * 3;
    const float* qc  = (dir ? tgt : src) + ((size_t)b * NP + qb * (WAVES * RF * 32)) * 3;

    // ---- stage DB chunk: 4 points/thread, pack A-layout into LDS ----
#pragma unroll
    for (int j = 0; j < 4; j++) {
        int i = tid + j * 256;
        float x = dbc[i * 3 + 0], y = dbc[i * 3 + 1], z = dbc[i * 3 + 2];
        Pack p = mkpack(x, y, z);
        uint4 h0, h1;
        h0.x = (unsigned)p.hx | ((unsigned)p.hx << 16);
        h0.y = (unsigned)p.lx | ((unsigned)p.hy << 16);
        h0.z = (unsigned)p.hy | ((unsigned)p.ly << 16);
        h0.w = (unsigned)p.hz | ((unsigned)p.hz << 16);
        h1.x = (unsigned)p.lz | ((unsigned)p.h2 << 16);
        h1.y = (unsigned)p.l2 | (ONE << 16);
        h1.z = ONE;
        h1.w = 0u;
        int f = i >> 5, m = i & 31;
        ash[f * 64 + m]      = h0;
        ash[f * 64 + 32 + m] = h1;
    }

    // ---- pack this lane's query B-frags in registers ----
    const int half = lane >> 5, m = lane & 31;
    bf16x8 qfrag[RF];
#pragma unroll
    for (int rf = 0; rf < RF; rf++) {
        int q = wave * (RF * 32) + rf * 32 + m;
        float x = qc[q * 3 + 0], y = qc[q * 3 + 1], z = qc[q * 3 + 2];
        Pack p = mkpack(x, y, z);
        unsigned short nhx = neg2(p.hx), nlx = neg2(p.lx);
        unsigned short nhy = neg2(p.hy), nly = neg2(p.ly);
        unsigned short nhz = neg2(p.hz), nlz = neg2(p.lz);
        uint4 v;
        if (half == 0) {
            v.x = (unsigned)nhx | ((unsigned)nlx << 16);
            v.y = (unsigned)nhx | ((unsigned)nhy << 16);
            v.z = (unsigned)nly | ((unsigned)nhy << 16);
            v.w = (unsigned)nhz | ((unsigned)nlz << 16);
        } else {
            v.x = (unsigned)nhz | (ONE << 16);
            v.y = ONE | ((unsigned)p.h2 << 16);
            v.z = (unsigned)p.l2;
            v.w = 0u;
        }
        qfrag[rf] = *(bf16x8*)&v;
    }

    int vmini[RF];
#pragma unroll
    for (int rf = 0; rf < RF; rf++) vmini[rf] = __float_as_int(1e30f);
    f32x16 zero = {};
    __syncthreads();                            // staging barrier

    for (int t = 0; t < CFRAGS; t += 2) {
        bf16x8 a0 = *(bf16x8*)&ash[t * 64 + lane];
        bf16x8 a1 = *(bf16x8*)&ash[(t + 1) * 64 + lane];
#pragma unroll
        for (int rf = 0; rf < RF; rf++) {
            f32x16 dA = __builtin_amdgcn_mfma_f32_32x32x16_bf16(a0, qfrag[rf], zero, 0, 0, 0);
            f32x16 dB = __builtin_amdgcn_mfma_f32_32x32x16_bf16(a1, qfrag[rf], zero, 0, 0, 0);
#pragma unroll
            for (int i = 0; i < 16; i++)
                vmini[rf] = smin3(__float_as_int(dA[i]), __float_as_int(dB[i]),
                                  vmini[rf]);           // v_min3_i32
        }
    }

    // finalize: lane^32 holds the other 16 DB rows of the same query column
    float* pbase = part + ((size_t)(dir * BB + b) * NCHG + ch) * NP
                 + qb * (WAVES * RF * 32) + wave * (RF * 32);
#pragma unroll
    for (int rf = 0; rf < RF; rf++) {
        float v = __int_as_float(vmini[rf]);
        v = fminf(v, __shfl_xor(v, 32, 64));
        if (lane < 32) pbase[rf * 32 + lane] = v;
    }

    // ---- fused finisher: last chunk-block of this (dir,b,qb) reduces it ----
    __threadfence();                            // release: part writes visible
    __shared__ int ticket;
    if (tid == 0)
        ticket = atomicAdd(&tickets[(dir * BB + b) * QBLOCKS + qb], 1);
    __syncthreads();
    if (ticket == NCHG - 1) {
        __threadfence();                        // acquire: others' parts visible
        const int q0 = qb * 512;
        const float* p = part + ((size_t)(dir * BB + b) * NCHG) * NP + q0;
        float v = 0.f;
#pragma unroll
        for (int jj = 0; jj < 2; jj++) {
            int j = tid + jj * 256;
            float mn = 1e30f;
#pragma unroll
            for (int i = 0; i < NCHG; i++) mn = fminf(mn, p[(size_t)i * NP + j]);
            float w = dir ? 1.0f : weights[b * NP + q0 + j];
            v += mn * w;
        }
        v *= (1.0f / BB);
#pragma unroll
        for (int off = 32; off; off >>= 1) v += __shfl_down(v, off, 64);
        __shared__ float ls[4];
        if ((tid & 63) == 0) ls[tid >> 6] = v;
        __syncthreads();
        if (tid == 0) atomicAdd(out, ls[0] + ls[1] + ls[2] + ls[3]);
    }
}

extern "C" void kernel_launch(void* const* d_in, const int* in_sizes, int n_in,
                              void* d_out, int out_size, void* d_ws, size_t ws_size,
                              hipStream_t stream) {
    const float* src = (const float*)d_in[0];   // (B, N, 3)
    const float* tgt = (const float*)d_in[1];   // (B, M, 3)
    const float* wgt = (const float*)d_in[2];   // (B, N)
    float* out = (float*)d_out;

    float* part    = (float*)d_ws;                              // 2 MB
    int*   tickets = (int*)((char*)d_ws + (size_t)2 * 1024 * 1024);  // 512 B

    hipMemsetAsync(tickets, 0, 2 * BB * QBLOCKS * sizeof(int), stream);
    hipMemsetAsync(out, 0, sizeof(float), stream);

    scan_kernel<<<dim3(QBLOCKS, BB, 2 * NCHG), dim3(256), 0, stream>>>(
        src, tgt, wgt, part, tickets, out);
}

// Round 19
// 76.749 us; speedup vs baseline: 2.0263x; 2.0263x over previous
//
#include <hip/hip_runtime.h>

// Weighted Chamfer, B=4, N=M=8192, D=3, fp32 in/out.
// out = (1/B)*[ sum_b sum_n w*min_m d2 + sum_b sum_m min_n d2 ]
//
// One v_mfma_f32_32x32x16_bf16 yields a 32x32 tile of d2 = s2 + t2 - 2 s.t
// via K-slot packing with split-bf16 compensation (verified r2-r17):
//   A(plain)  half0 {hx,hx,lx,hy,hy,ly,hz,hz} half1 {lz,h2,l2,1,1,0,0,0}
//   B(-2 scl) half0 {nhx,nlx,nhx,nhy,nly,nhy,nhz,nlz} half1 {nhz,1,1,h2,l2,0,0,0}
//   Error ~1e-5 (threshold 5.76). C/D layout: col=lane&31.
// Transposed operands (r8): DB = A staged in LDS, queries = B in registers ->
// per-lane scalar running min. i32-domain min (r13) folds to v_min3_i32.
// Self-packing (r14): no prep kernel; -2*bf16 in int bits ((h^0x8000)+0x80).
// Reg rule (r16): body needs >= ~100-reg budget; launch_bounds(256,4) only.
// Fence rule (r18): per-block __threadfence() on gfx950 = L2 wb/inv + vmcnt
// drain -> 1024 blocks serialized (~90 us scan). Separate reduce launch is
// the cheap synchronization; fused finishers are falsified.
//
// Round 19: restore the verified best (r14 = r17, 76.9/77.5 us). Budget:
// ~40.5 us immovable harness ws re-poison (84% HBM peak) + ~6 us harness
// restore/gaps + scan ~22 us (dual-pipe issue-saturated: r11's REP counters
// MfmaUtil 44% + VALUBusy 52% = 96%) + reduce ~2.5 us + dispatch gap.

typedef short bf16x8 __attribute__((ext_vector_type(8)));
typedef float f32x16 __attribute__((ext_vector_type(16)));

#define BB 4
#define NP 8192
#define RF 4                     // query-frags per wave (128 queries)
#define WAVES 4                  // 256 threads; 512 queries per block
#define QBLOCKS 16               // 8192 / 512
#define CFRAGS 32                // DB frags per LDS stage (1024 pts, 32 KB)
#define NCHG 8                   // DB chunks (8192 / 1024)

__device__ __forceinline__ int smin3(int a, int b, int c) {
    int m = a < b ? a : b;
    return (m < c) ? m : c;      // folds to v_min3_i32
}
__device__ __forceinline__ unsigned short bf16r(float x) {
    unsigned u = __float_as_uint(x);
    unsigned r = u + 0x7FFFu + ((u >> 16) & 1u);
    return (unsigned short)(r >> 16);
}
__device__ __forceinline__ float bf16f(unsigned short h) {
    return __uint_as_float(((unsigned)h) << 16);
}
// -2 * bf16(h), exact in bits (sign flip + exponent+1); h==+-0 -> tiny
// denormal ~1e-38 whose products are << 1e-5 packing error.
__device__ __forceinline__ unsigned short neg2(unsigned short h) {
    return (unsigned short)((h ^ 0x8000u) + 0x0080u);
}

struct Pack {
    unsigned short hx, lx, hy, ly, hz, lz, h2, l2;
};
__device__ __forceinline__ Pack mkpack(float x, float y, float z) {
    Pack p;
    p.hx = bf16r(x); p.lx = bf16r(x - bf16f(p.hx));
    p.hy = bf16r(y); p.ly = bf16r(y - bf16f(p.hy));
    p.hz = bf16r(z); p.lz = bf16r(z - bf16f(p.hz));
    float n2 = x * x + y * y + z * z;
    p.h2 = bf16r(n2); p.l2 = bf16r(n2 - bf16f(p.h2));
    return p;
}

#define ONE 0x3F80u

// ---- scan: self-packing; DB rows from LDS, queries in regs, i32 min3 ----
__global__ __launch_bounds__(256, 4) void scan_kernel(
    const float* __restrict__ src, const float* __restrict__ tgt,
    float* __restrict__ part,   // part[dir][b][ch][query]
    float* __restrict__ out)
{
    __shared__ uint4 ash[CFRAGS * 64];          // 32 KB DB stage (A-packs)
    const int tid = threadIdx.x;
    const int lane = tid & 63, wave = tid >> 6;
    const int qb = blockIdx.x, b = blockIdx.y;
    const int dir = blockIdx.z >> 3, ch = blockIdx.z & (NCHG - 1);

    if (blockIdx.x == 0 && blockIdx.y == 0 && blockIdx.z == 0 && tid == 0)
        out[0] = 0.0f;

    // dir 0: queries = source, DB = target; dir 1 mirrored.
    const float* dbc = (dir ? src : tgt) + ((size_t)b * NP + ch * 1024) * 3;
    const float* qc  = (dir ? tgt : src) + ((size_t)b * NP + qb * (WAVES * RF * 32)) * 3;

    // ---- stage DB chunk: 4 points/thread, pack A-layout into LDS ----
#pragma unroll
    for (int j = 0; j < 4; j++) {
        int i = tid + j * 256;
        float x = dbc[i * 3 + 0], y = dbc[i * 3 + 1], z = dbc[i * 3 + 2];
        Pack p = mkpack(x, y, z);
        uint4 h0, h1;
        h0.x = (unsigned)p.hx | ((unsigned)p.hx << 16);
        h0.y = (unsigned)p.lx | ((unsigned)p.hy << 16);
        h0.z = (unsigned)p.hy | ((unsigned)p.ly << 16);
        h0.w = (unsigned)p.hz | ((unsigned)p.hz << 16);
        h1.x = (unsigned)p.lz | ((unsigned)p.h2 << 16);
        h1.y = (unsigned)p.l2 | (ONE << 16);
        h1.z = ONE;
        h1.w = 0u;
        int f = i >> 5, m = i & 31;
        ash[f * 64 + m]      = h0;
        ash[f * 64 + 32 + m] = h1;
    }

    // ---- pack this lane's query B-frags in registers ----
    const int half = lane >> 5, m = lane & 31;
    bf16x8 qfrag[RF];
#pragma unroll
    for (int rf = 0; rf < RF; rf++) {
        int q = wave * (RF * 32) + rf * 32 + m;
        float x = qc[q * 3 + 0], y = qc[q * 3 + 1], z = qc[q * 3 + 2];
        Pack p = mkpack(x, y, z);
        unsigned short nhx = neg2(p.hx), nlx = neg2(p.lx);
        unsigned short nhy = neg2(p.hy), nly = neg2(p.ly);
        unsigned short nhz = neg2(p.hz), nlz = neg2(p.lz);
        uint4 v;
        if (half == 0) {
            v.x = (unsigned)nhx | ((unsigned)nlx << 16);
            v.y = (unsigned)nhx | ((unsigned)nhy << 16);
            v.z = (unsigned)nly | ((unsigned)nhy << 16);
            v.w = (unsigned)nhz | ((unsigned)nlz << 16);
        } else {
            v.x = (unsigned)nhz | (ONE << 16);
            v.y = ONE | ((unsigned)p.h2 << 16);
            v.z = (unsigned)p.l2;
            v.w = 0u;
        }
        qfrag[rf] = *(bf16x8*)&v;
    }

    int vmini[RF];
#pragma unroll
    for (int rf = 0; rf < RF; rf++) vmini[rf] = __float_as_int(1e30f);
    f32x16 zero = {};
    __syncthreads();                            // the block's only barrier

    for (int t = 0; t < CFRAGS; t += 2) {
        bf16x8 a0 = *(bf16x8*)&ash[t * 64 + lane];
        bf16x8 a1 = *(bf16x8*)&ash[(t + 1) * 64 + lane];
#pragma unroll
        for (int rf = 0; rf < RF; rf++) {
            f32x16 dA = __builtin_amdgcn_mfma_f32_32x32x16_bf16(a0, qfrag[rf], zero, 0, 0, 0);
            f32x16 dB = __builtin_amdgcn_mfma_f32_32x32x16_bf16(a1, qfrag[rf], zero, 0, 0, 0);
#pragma unroll
            for (int i = 0; i < 16; i++)
                vmini[rf] = smin3(__float_as_int(dA[i]), __float_as_int(dB[i]),
                                  vmini[rf]);           // v_min3_i32
        }
    }

    // finalize: lane^32 holds the other 16 DB rows of the same query column
    float* pbase = part + ((size_t)(dir * BB + b) * NCHG + ch) * NP
                 + qb * (WAVES * RF * 32) + wave * (RF * 32);
#pragma unroll
    for (int rf = 0; rf < RF; rf++) {
        float v = __int_as_float(vmini[rf]);
        v = fminf(v, __shfl_xor(v, 32, 64));
        if (lane < 32) pbase[rf * 32 + lane] = v;
    }
}

// ---- reduce: min over DB chunks, weight, sum, atomicAdd ----
__global__ __launch_bounds__(256) void reduce_kernel(
    const float* __restrict__ weights, const float* __restrict__ part,
    float* __restrict__ out)
{
    int tid = threadIdx.x;
    int gid = blockIdx.x * 256 + tid;       // 0 .. 65535
    int dir = gid >> 15;
    int r   = gid & 32767;
    int b   = r >> 13;
    int q   = r & (NP - 1);

    const float* p = part + ((size_t)(dir * BB + b) * NCHG) * NP + q;
    float mn = 1e30f;
#pragma unroll
    for (int i = 0; i < NCHG; i++) mn = fminf(mn, p[(size_t)i * NP]);
    float w = dir ? 1.0f : weights[b * NP + q];
    float v = mn * w * (1.0f / BB);
#pragma unroll
    for (int off = 32; off; off >>= 1) v += __shfl_down(v, off, 64);
    __shared__ float ls[4];
    if ((tid & 63) == 0) ls[tid >> 6] = v;
    __syncthreads();
    if (tid == 0) atomicAdd(out, ls[0] + ls[1] + ls[2] + ls[3]);
}

extern "C" void kernel_launch(void* const* d_in, const int* in_sizes, int n_in,
                              void* d_out, int out_size, void* d_ws, size_t ws_size,
                              hipStream_t stream) {
    const float* src = (const float*)d_in[0];   // (B, N, 3)
    const float* tgt = (const float*)d_in[1];   // (B, M, 3)
    const float* wgt = (const float*)d_in[2];   // (B, N)
    float* out = (float*)d_out;

    float* part = (float*)d_ws;                 // 2 MB: [2][BB][NCHG][NP]

    scan_kernel<<<dim3(QBLOCKS, BB, 2 * NCHG), dim3(256), 0, stream>>>(
        src, tgt, part, out);
    reduce_kernel<<<dim3(256), dim3(256), 0, stream>>>(wgt, part, out);
}